// Round 6
// baseline (91.881 us; speedup 1.0000x reference)
//
#include <hip/hip_runtime.h>

#define SS 304
#define HH 228
#define WW 304
#define FARV 100.0f
#define EPSV 1e-07f
#define SPLIT 16         // face-range slices (gridDim.z)
#define CH 128           // faces per slice == one staging chunk
#define TILE 32          // pixel tile is 32x32
// block: 16x8 threads (2 waves); each thread covers 2(px in x) x 4(px in y)

// per-vertex transform (contract off, IEEE divides — once per face, cheap)
__device__ __forceinline__ void xform_vertex(
    float u, float v, float d,
    float fx, float cx, float fy, float cy,
    float r00, float r01, float r02,
    float r10, float r11, float r12,
    float r20, float r21, float r22,
    float t0, float t1, float t2,
    float& xn, float& yn, float& z)
{
#pragma clang fp contract(off)
    float ki00 = 1.0f / fx;
    float ki02 = -(cx / fx);
    float ki11 = 1.0f / fy;
    float ki12 = -(cy / fy);
    float px = u * (float)WW;
    float py = v * (float)HH;
    float c0 = (ki00 * px + ki02) * d;
    float c1 = (ki11 * py + ki12) * d;
    float c2 = d;
    float e0 = ((r00*c0 + r01*c1) + r02*c2) + t0;
    float e1 = ((r10*c0 + r11*c1) + r12*c2) + t1;
    float e2 = ((r20*c0 + r21*c1) + r22*c2) + t2;
    z = e2;
    float zd = z + EPSV;
    float p0 = e0 / zd;
    float p1 = e1 / zd;
    float q0 = p0 * fx + cx;
    float q1 = p1 * fy + cy;
    float uu = q0 / (float)WW; uu = fminf(fmaxf(uu, 0.0f), 1.0f);
    float vv = q1 / (float)HH; vv = fminf(fmaxf(vv, 0.0f), 1.0f);
    xn = uu * (float)WW / (float)SS * 2.0f - 1.0f;
    yn = vv * (float)HH / (float)SS * 2.0f - 1.0f;
}

// ---- Kernel 1: out init + per-face transform + normalized plane precompute ----
// Normalized barycentric planes (divide by |denom|):
//   w0(X,Y) = a0*X + b0*Y + c0,  w1(X,Y) = a1*X + b1*Y + c1
//   inside <=> w0>=0 && w1>=0 && (1-w0)-w1>=0
//   iz(X,Y) = E*X + F*Y + G  (interpolated 1/z plane)
__global__ __launch_bounds__(256) void prep_kernel(
    const float* __restrict__ verts,
    const int* __restrict__ faces,
    const float* __restrict__ Km,
    const float* __restrict__ Rm,
    const float* __restrict__ tm,
    float4* __restrict__ bboxArr,
    float4* __restrict__ P0arr,   // a0,b0,c0,a1
    float4* __restrict__ P1arr,   // b1,c1,E,F
    float*  __restrict__ Garr,    // G
    float* __restrict__ out, int M)
{
#pragma clang fp contract(off)
    int g = blockIdx.x * blockDim.x + threadIdx.x;
    if (g < HH * WW) {
        out[g] = FARV;
        out[HH * WW + g] = 0.0f;
    }
    if (g >= M) return;
    int m = g;
    int i0 = faces[3*m+0], i1 = faces[3*m+1], i2 = faces[3*m+2];
    float fx = Km[0], cx = Km[2], fy = Km[4], cy = Km[5];
    float r00 = Rm[0], r01 = Rm[1], r02 = Rm[2];
    float r10 = Rm[3], r11 = Rm[4], r12 = Rm[5];
    float r20 = Rm[6], r21 = Rm[7], r22 = Rm[8];
    float t0 = tm[0], t1 = tm[1], t2 = tm[2];

    float x0, y0, z0, x1, y1, z1, x2, y2, z2;
    xform_vertex(verts[3*i0+0], verts[3*i0+1], verts[3*i0+2], fx,cx,fy,cy,
                 r00,r01,r02,r10,r11,r12,r20,r21,r22,t0,t1,t2, x0,y0,z0);
    xform_vertex(verts[3*i1+0], verts[3*i1+1], verts[3*i1+2], fx,cx,fy,cy,
                 r00,r01,r02,r10,r11,r12,r20,r21,r22,t0,t1,t2, x1,y1,z1);
    xform_vertex(verts[3*i2+0], verts[3*i2+1], verts[3*i2+2], fx,cx,fy,cy,
                 r00,r01,r02,r10,r11,r12,r20,r21,r22,t0,t1,t2, x2,y2,z2);

    float A0 = y1 - y2;
    float B0 = x2 - x1;
    float A1 = y2 - y0;
    float B1 = x0 - x2;
    float dy02 = y0 - y2;
    float denom = A0 * B1 + B0 * dy02;
    bool ok = fabsf(denom) > 1e-10f;

    float xmin, xmax, ymin, ymax;
    if (ok) {
        xmin = fminf(x0, fminf(x1, x2)) - 1e-4f;
        xmax = fmaxf(x0, fmaxf(x1, x2)) + 1e-4f;
        ymin = fminf(y0, fminf(y1, y2)) - 1e-4f;
        ymax = fmaxf(y0, fmaxf(y1, y2)) + 1e-4f;
    } else {
        xmin = 1e30f; xmax = -1e30f; ymin = 1e30f; ymax = -1e30f;
    }
    bboxArr[m] = make_float4(xmin, xmax, ymin, ymax);

    // normalized planes: divide everything by denom (signed -> handles flip)
    float rs = 1.0f / denom;                 // safe: degenerate never staged
    float a0 = A0 * rs, b0 = B0 * rs;
    float c0 = -(a0 * x2 + b0 * y2);
    float a1 = A1 * rs, b1 = B1 * rs;
    float c1 = -(a1 * x2 + b1 * y2);
    float rz0 = 1.0f / z0, rz1 = 1.0f / z1, rz2 = 1.0f / z2;
    float u = rz0 - rz2, v = rz1 - rz2;
    // iz = rz2 + w0*u + w1*v  -> plane E,F,G
    float E = a0 * u + a1 * v;
    float F = b0 * u + b1 * v;
    float G = (c0 * u + c1 * v) + rz2;

    P0arr[m] = make_float4(a0, b0, c0, a1);
    P1arr[m] = make_float4(b1, c1, E, F);
    Garr[m]  = G;
}

// ---- Kernel 2: rasterize; 32x32 tile, 2x4 px/thread, LDS reads amortized ----
__global__ __launch_bounds__(128) void raster_kernel(
    const float4* __restrict__ bboxArr,
    const float4* __restrict__ P0arr,
    const float4* __restrict__ P1arr,
    const float*  __restrict__ Garr,
    float* __restrict__ out, int M)
{
    __shared__ float4 sP0[CH];
    __shared__ float4 sP1[CH];
    __shared__ float  sG[CH];
    __shared__ int sCount;

    int tx = threadIdx.x;              // 0..15
    int ty = threadIdx.y;              // 0..7
    int tid = ty * 16 + tx;            // 0..127

    int wbase = blockIdx.x * TILE;
    int hbase = blockIdx.y * TILE;

    // tile NDC bounds for culling
    int whi = min(wbase + TILE - 1, WW - 1);
    int hhi = min(hbase + TILE - 1, HH - 1);
    float txlo = ((float)(2*wbase + 1 - SS)) / (float)SS;
    float txhi = ((float)(2*whi   + 1 - SS)) / (float)SS;
    float tylo = ((float)(2*(SS-1-hhi)   + 1 - SS)) / (float)SS;
    float tyhi = ((float)(2*(SS-1-hbase) + 1 - SS)) / (float)SS;

    if (tid == 0) sCount = 0;
    __syncthreads();

    {   // cooperative staging: CH==128 faces, one per thread
        int m = blockIdx.z * CH + tid;   // M == SPLIT*CH == 2048
        float4 rb = bboxArr[m];
        bool pass = !(rb.x > txhi || rb.y < txlo || rb.z > tyhi || rb.w < tylo);
        if (pass) {
            int i = atomicAdd(&sCount, 1);
            sP0[i] = P0arr[m];
            sP1[i] = P1arr[m];
            sG[i]  = Garr[m];
        }
    }
    __syncthreads();
    int cnt = sCount;

    // this thread's 2x4 pixel footprint
    int w0px = wbase + 2 * tx;           // x: w0px, w0px+1
    int h0px = hbase + 4 * ty;           // y: h0px .. h0px+3
    float XP0 = ((float)(2*w0px + 1 - SS)) / (float)SS;
    float YP0 = ((float)(SS - 1 - 2*h0px)) / (float)SS;   // YP(h)=(S-1-2h)/S
    const float dx = 2.0f / (float)SS;    // XP(w+1)-XP(w)
    const float dy = -2.0f / (float)SS;   // YP(h+1)-YP(h)

    float mx[4][2] = {{0,0},{0,0},{0,0},{0,0}};  // running max iz per pixel

    for (int k = 0; k < cnt; ++k) {
        float4 g0 = sP0[k];   // a0,b0,c0,a1
        float4 g1 = sP1[k];   // b1,c1,E,F
        float  G  = sG[k];
        float a0 = g0.x, b0 = g0.y, c0 = g0.z, a1 = g0.w;
        float b1 = g1.x, c1 = g1.y, E = g1.z, F = g1.w;

        float p0 = fmaf(a0, XP0, fmaf(b0, YP0, c0));
        float p1 = fmaf(a1, XP0, fmaf(b1, YP0, c1));
        float pz = fmaf(E,  XP0, fmaf(F,  YP0, G));
        float a0dx = a0 * dx, a1dx = a1 * dx, Edx = E * dx;
        float b0dy = b0 * dy, b1dy = b1 * dy, Fdy = F * dy;

#pragma unroll
        for (int yy = 0; yy < 4; ++yy) {
            // left pixel
            float w2 = (1.0f - p0) - p1;
            float m3 = fminf(fminf(p0, p1), w2);
            mx[yy][0] = fmaxf(mx[yy][0], (m3 >= 0.0f) ? pz : 0.0f);
            // right pixel (incremental)
            float q0 = p0 + a0dx;
            float q1 = p1 + a1dx;
            float qz = pz + Edx;
            float w2r = (1.0f - q0) - q1;
            float m3r = fminf(fminf(q0, q1), w2r);
            mx[yy][1] = fmaxf(mx[yy][1], (m3r >= 0.0f) ? qz : 0.0f);
            // next row
            p0 += b0dy; p1 += b1dy; pz += Fdy;
        }
    }

    // write back: depth = 1/max(iz) (rcp monotone on positives)
#pragma unroll
    for (int yy = 0; yy < 4; ++yy) {
        int h = h0px + yy;
        if (h >= HH) break;
#pragma unroll
        for (int xx = 0; xx < 2; ++xx) {
            int w = w0px + xx;
            if (w >= WW) continue;
            float m = mx[yy][xx];
            if (m > 0.0f) {
                float depth = __builtin_amdgcn_rcpf(m);
                atomicMin((unsigned int*)&out[h * WW + w], __float_as_uint(depth));
                atomicMax((unsigned int*)&out[HH * WW + h * WW + w],
                          __float_as_uint(1.0f));
            }
        }
    }
}

extern "C" void kernel_launch(void* const* d_in, const int* in_sizes, int n_in,
                              void* d_out, int out_size, void* d_ws, size_t ws_size,
                              hipStream_t stream) {
    const float* verts = (const float*)d_in[0];
    const int*   faces = (const int*)d_in[1];
    const float* K     = (const float*)d_in[2];
    const float* R     = (const float*)d_in[3];
    const float* t     = (const float*)d_in[4];
    float* out = (float*)d_out;

    int M = in_sizes[1] / 3;   // 2048

    char* ws = (char*)d_ws;
    float4* bbox = (float4*)ws;                ws += (size_t)M * sizeof(float4);
    float4* P0   = (float4*)ws;                ws += (size_t)M * sizeof(float4);
    float4* P1   = (float4*)ws;                ws += (size_t)M * sizeof(float4);
    float*  G    = (float*)ws;                 ws += (size_t)M * sizeof(float);

    prep_kernel<<<(HH * WW + 255) / 256, 256, 0, stream>>>(
        verts, faces, K, R, t, bbox, P0, P1, G, out, M);

    dim3 blk(16, 8);
    dim3 grd((WW + TILE - 1) / TILE, (HH + TILE - 1) / TILE, SPLIT);
    raster_kernel<<<grd, blk, 0, stream>>>(bbox, P0, P1, G, out, M);
}

// Round 7
// 90.345 us; speedup vs baseline: 1.0170x; 1.0170x over previous
//
#include <hip/hip_runtime.h>

#define SS 304
#define HH 228
#define WW 304
#define HPW (HH * WW)
#define FARV 100.0f
#define EPSV 1e-07f
#define SPLIT 8          // face-range slices (gridDim.z); M == SPLIT*CH
#define CH 256           // faces per slice
#define TILE 16          // pixel tile 16x16; block 8x8 threads, 2x2 px/thread

// per-vertex transform (contract off, IEEE divides — once per face, cheap)
__device__ __forceinline__ void xform_vertex(
    float u, float v, float d,
    float fx, float cx, float fy, float cy,
    float r00, float r01, float r02,
    float r10, float r11, float r12,
    float r20, float r21, float r22,
    float t0, float t1, float t2,
    float& xn, float& yn, float& z)
{
#pragma clang fp contract(off)
    float ki00 = 1.0f / fx;
    float ki02 = -(cx / fx);
    float ki11 = 1.0f / fy;
    float ki12 = -(cy / fy);
    float px = u * (float)WW;
    float py = v * (float)HH;
    float c0 = (ki00 * px + ki02) * d;
    float c1 = (ki11 * py + ki12) * d;
    float c2 = d;
    float e0 = ((r00*c0 + r01*c1) + r02*c2) + t0;
    float e1 = ((r10*c0 + r11*c1) + r12*c2) + t1;
    float e2 = ((r20*c0 + r21*c1) + r22*c2) + t2;
    z = e2;
    float zd = z + EPSV;
    float p0 = e0 / zd;
    float p1 = e1 / zd;
    float q0 = p0 * fx + cx;
    float q1 = p1 * fy + cy;
    float uu = q0 / (float)WW; uu = fminf(fmaxf(uu, 0.0f), 1.0f);
    float vv = q1 / (float)HH; vv = fminf(fmaxf(vv, 0.0f), 1.0f);
    xn = uu * (float)WW / (float)SS * 2.0f - 1.0f;
    yn = vv * (float)HH / (float)SS * 2.0f - 1.0f;
}

// ---- Kernel 1: per-face transform + normalized plane precompute ----
//   w0(X,Y)=a0*X+b0*Y+c0, w1(X,Y)=a1*X+b1*Y+c1, inside <=> min(w0,w1,(1-w0)-w1)>=0
//   iz(X,Y)=E*X+F*Y+G (interpolated 1/z plane)
__global__ __launch_bounds__(256) void prep_kernel(
    const float* __restrict__ verts,
    const int* __restrict__ faces,
    const float* __restrict__ Km,
    const float* __restrict__ Rm,
    const float* __restrict__ tm,
    float4* __restrict__ bboxArr,
    float4* __restrict__ P0arr,   // a0,b0,c0,a1
    float4* __restrict__ P1arr,   // b1,c1,E,F
    float*  __restrict__ Garr,    // G
    int M)
{
#pragma clang fp contract(off)
    int m = blockIdx.x * blockDim.x + threadIdx.x;
    if (m >= M) return;
    int i0 = faces[3*m+0], i1 = faces[3*m+1], i2 = faces[3*m+2];
    float fx = Km[0], cx = Km[2], fy = Km[4], cy = Km[5];
    float r00 = Rm[0], r01 = Rm[1], r02 = Rm[2];
    float r10 = Rm[3], r11 = Rm[4], r12 = Rm[5];
    float r20 = Rm[6], r21 = Rm[7], r22 = Rm[8];
    float t0 = tm[0], t1 = tm[1], t2 = tm[2];

    float x0, y0, z0, x1, y1, z1, x2, y2, z2;
    xform_vertex(verts[3*i0+0], verts[3*i0+1], verts[3*i0+2], fx,cx,fy,cy,
                 r00,r01,r02,r10,r11,r12,r20,r21,r22,t0,t1,t2, x0,y0,z0);
    xform_vertex(verts[3*i1+0], verts[3*i1+1], verts[3*i1+2], fx,cx,fy,cy,
                 r00,r01,r02,r10,r11,r12,r20,r21,r22,t0,t1,t2, x1,y1,z1);
    xform_vertex(verts[3*i2+0], verts[3*i2+1], verts[3*i2+2], fx,cx,fy,cy,
                 r00,r01,r02,r10,r11,r12,r20,r21,r22,t0,t1,t2, x2,y2,z2);

    float A0 = y1 - y2;
    float B0 = x2 - x1;
    float A1 = y2 - y0;
    float B1 = x0 - x2;
    float dy02 = y0 - y2;
    float denom = A0 * B1 + B0 * dy02;
    bool ok = fabsf(denom) > 1e-10f;

    float xmin, xmax, ymin, ymax;
    if (ok) {
        xmin = fminf(x0, fminf(x1, x2)) - 1e-4f;
        xmax = fmaxf(x0, fmaxf(x1, x2)) + 1e-4f;
        ymin = fminf(y0, fminf(y1, y2)) - 1e-4f;
        ymax = fmaxf(y0, fmaxf(y1, y2)) + 1e-4f;
    } else {
        xmin = 1e30f; xmax = -1e30f; ymin = 1e30f; ymax = -1e30f;  // never staged
    }
    bboxArr[m] = make_float4(xmin, xmax, ymin, ymax);

    float rs = 1.0f / denom;                 // degenerate never staged
    float a0 = A0 * rs, b0 = B0 * rs;
    float c0 = -(a0 * x2 + b0 * y2);
    float a1 = A1 * rs, b1 = B1 * rs;
    float c1 = -(a1 * x2 + b1 * y2);
    float rz0 = 1.0f / z0, rz1 = 1.0f / z1, rz2 = 1.0f / z2;
    float uu = rz0 - rz2, vv = rz1 - rz2;
    float E = a0 * uu + a1 * vv;
    float F = b0 * uu + b1 * vv;
    float G = (c0 * uu + c1 * vv) + rz2;

    P0arr[m] = make_float4(a0, b0, c0, a1);
    P1arr[m] = make_float4(b1, c1, E, F);
    Garr[m]  = G;
}

// ---- Kernel 2: rasterize; per-(tile,slice) max-iz, plain stores, NO atomics ----
__global__ __launch_bounds__(64) void raster_kernel(
    const float4* __restrict__ bboxArr,
    const float4* __restrict__ P0arr,
    const float4* __restrict__ P1arr,
    const float*  __restrict__ Garr,
    float* __restrict__ slice)
{
    __shared__ float4 sP0[CH];
    __shared__ float4 sP1[CH];
    __shared__ float  sG[CH];
    __shared__ int sCount;

    int tx = threadIdx.x;              // 0..7
    int ty = threadIdx.y;              // 0..7
    int tid = ty * 8 + tx;             // 0..63

    int wbase = blockIdx.x * TILE;
    int hbase = blockIdx.y * TILE;

    // tile NDC bounds for culling
    int whi = min(wbase + TILE - 1, WW - 1);
    int hhi = min(hbase + TILE - 1, HH - 1);
    float txlo = ((float)(2*wbase + 1 - SS)) / (float)SS;
    float txhi = ((float)(2*whi   + 1 - SS)) / (float)SS;
    float tylo = ((float)(2*(SS-1-hhi)   + 1 - SS)) / (float)SS;
    float tyhi = ((float)(2*(SS-1-hbase) + 1 - SS)) / (float)SS;

    if (tid == 0) sCount = 0;
    __syncthreads();

    // cooperative staging: CH faces, 4 per thread, compact survivors
#pragma unroll
    for (int j = 0; j < CH / 64; ++j) {
        int m = blockIdx.z * CH + j * 64 + tid;
        float4 rb = bboxArr[m];
        bool pass = !(rb.x > txhi || rb.y < txlo || rb.z > tyhi || rb.w < tylo);
        if (pass) {
            int i = atomicAdd(&sCount, 1);
            sP0[i] = P0arr[m];
            sP1[i] = P1arr[m];
            sG[i]  = Garr[m];
        }
    }
    __syncthreads();
    int cnt = sCount;

    // this thread's 2x2 pixel footprint
    int w0px = wbase + 2 * tx;
    int h0px = hbase + 2 * ty;
    float XP0 = ((float)(2*w0px + 1 - SS)) / (float)SS;
    float YP0 = ((float)(SS - 1 - 2*h0px)) / (float)SS;
    const float dxx = 2.0f / (float)SS;
    const float dyy = -2.0f / (float)SS;

    float m00 = 0.0f, m10 = 0.0f, m01 = 0.0f, m11 = 0.0f;  // max iz per px

    for (int k = 0; k < cnt; ++k) {
        float4 g0 = sP0[k];   // a0,b0,c0,a1
        float4 g1 = sP1[k];   // b1,c1,E,F
        float  G  = sG[k];
        float a0 = g0.x, b0 = g0.y, c0 = g0.z, a1 = g0.w;
        float b1 = g1.x, c1 = g1.y, E = g1.z, F = g1.w;

        float p0 = fmaf(a0, XP0, fmaf(b0, YP0, c0));
        float p1 = fmaf(a1, XP0, fmaf(b1, YP0, c1));
        float pz = fmaf(E,  XP0, fmaf(F,  YP0, G));
        float a0x = a0 * dxx, a1x = a1 * dxx, Ex = E * dxx;
        float b0y = b0 * dyy, b1y = b1 * dyy, Fy = F * dyy;

        // (0,0)
        float w2 = (1.0f - p0) - p1;
        float m3 = fminf(fminf(p0, p1), w2);
        m00 = fmaxf(m00, (m3 >= 0.0f) ? pz : 0.0f);
        // (1,0)
        float q0 = p0 + a0x, q1 = p1 + a1x, qz = pz + Ex;
        float w2b = (1.0f - q0) - q1;
        float m3b = fminf(fminf(q0, q1), w2b);
        m10 = fmaxf(m10, (m3b >= 0.0f) ? qz : 0.0f);
        // (0,1)
        float r0 = p0 + b0y, r1 = p1 + b1y, rz = pz + Fy;
        float w2c = (1.0f - r0) - r1;
        float m3c = fminf(fminf(r0, r1), w2c);
        m01 = fmaxf(m01, (m3c >= 0.0f) ? rz : 0.0f);
        // (1,1)
        float s0 = q0 + b0y, s1 = q1 + b1y, sz = qz + Fy;
        float w2d = (1.0f - s0) - s1;
        float m3d = fminf(fminf(s0, s1), w2d);
        m11 = fmaxf(m11, (m3d >= 0.0f) ? sz : 0.0f);
    }

    // plain coalesced stores to this slice's private buffer
    float* sb = slice + (size_t)blockIdx.z * HPW;
    if (h0px < HH) {
        float2 v = make_float2(m00, m10);
        *(float2*)&sb[h0px * WW + w0px] = v;
    }
    if (h0px + 1 < HH) {
        float2 v = make_float2(m01, m11);
        *(float2*)&sb[(h0px + 1) * WW + w0px] = v;
    }
}

// ---- Kernel 3: merge slices -> depth + silhouette ----
__global__ __launch_bounds__(256) void merge_kernel(
    const float* __restrict__ slice, float* __restrict__ out)
{
    int i = blockIdx.x * blockDim.x + threadIdx.x;
    if (i >= HPW) return;
    float mx = slice[i];
#pragma unroll
    for (int s = 1; s < SPLIT; ++s)
        mx = fmaxf(mx, slice[(size_t)s * HPW + i]);
    float depth = FARV, sil = 0.0f;
    if (mx > 0.0f) {
        depth = __builtin_amdgcn_rcpf(mx);   // rcp monotone: 1/max(iz)=min depth
        sil = 1.0f;
    }
    out[i] = depth;
    out[HPW + i] = sil;
}

extern "C" void kernel_launch(void* const* d_in, const int* in_sizes, int n_in,
                              void* d_out, int out_size, void* d_ws, size_t ws_size,
                              hipStream_t stream) {
    const float* verts = (const float*)d_in[0];
    const int*   faces = (const int*)d_in[1];
    const float* K     = (const float*)d_in[2];
    const float* R     = (const float*)d_in[3];
    const float* t     = (const float*)d_in[4];
    float* out = (float*)d_out;

    int M = in_sizes[1] / 3;   // 2048 == SPLIT*CH

    char* ws = (char*)d_ws;
    float4* bbox = (float4*)ws;                ws += (size_t)M * sizeof(float4);
    float4* P0   = (float4*)ws;                ws += (size_t)M * sizeof(float4);
    float4* P1   = (float4*)ws;                ws += (size_t)M * sizeof(float4);
    float*  G    = (float*)ws;                 ws += (size_t)M * sizeof(float);
    float*  slice= (float*)ws;                 ws += (size_t)SPLIT * HPW * sizeof(float);

    prep_kernel<<<(M + 255) / 256, 256, 0, stream>>>(
        verts, faces, K, R, t, bbox, P0, P1, G, M);

    dim3 blk(8, 8);
    dim3 grd((WW + TILE - 1) / TILE, (HH + TILE - 1) / TILE, SPLIT);
    raster_kernel<<<grd, blk, 0, stream>>>(bbox, P0, P1, G, slice);

    merge_kernel<<<(HPW + 255) / 256, 256, 0, stream>>>(slice, out);
}